// Round 4
// baseline (1772.899 us; speedup 1.0000x reference)
//
#include <hip/hip_runtime.h>
#include <math.h>
#include <float.h>

#define NN 100000
#define NE 1600000
#define ETOT 1700000   // NE + NN self loops
#define DIN 264
#define DH 64
#define SLOPE 0.2f

__global__ void k_mean(const float* __restrict__ ea, float* __restrict__ sum) {
  float acc = 0.f;
  for (int i = blockIdx.x * blockDim.x + threadIdx.x; i < NE; i += gridDim.x * blockDim.x)
    acc += ea[i];
  #pragma unroll
  for (int off = 32; off > 0; off >>= 1) acc += __shfl_xor(acc, off);
  __shared__ float s[4];
  int lane = threadIdx.x & 63, w = threadIdx.x >> 6;
  if (lane == 0) s[w] = acc;
  __syncthreads();
  if (threadIdx.x == 0) atomicAdd(sum, s[0] + s[1] + s[2] + s[3]);
}

__global__ void k_hist(const int* __restrict__ ei, unsigned* __restrict__ deg) {
  int e = blockIdx.x * blockDim.x + threadIdx.x;
  if (e >= ETOT) return;
  int d = (e < NE) ? ei[NE + e] : e - NE;
  atomicAdd(&deg[d], 1u);
}

// single-block exclusive scan of deg -> rowptr (and wptr cursor copy)
__global__ void k_scan(const unsigned* __restrict__ deg, unsigned* __restrict__ rowptr,
                       unsigned* __restrict__ wptr) {
  __shared__ unsigned ls[1024];
  const int CH = (NN + 1023) / 1024;  // 98
  int t = threadIdx.x;
  int beg = t * CH, end = min(beg + CH, NN);
  unsigned s = 0;
  for (int i = beg; i < end; i++) s += deg[i];
  ls[t] = s;
  __syncthreads();
  for (int off = 1; off < 1024; off <<= 1) {
    unsigned v = (t >= off) ? ls[t - off] : 0u;
    __syncthreads();
    ls[t] += v;
    __syncthreads();
  }
  unsigned base = (t == 0) ? 0u : ls[t - 1];
  for (int i = beg; i < end; i++) {
    rowptr[i] = base;
    wptr[i] = base;
    base += deg[i];
  }
  if (t == 1023) rowptr[NN] = ls[1023];
}

__global__ void k_scatter(const int* __restrict__ ei, const float* __restrict__ ea,
                          const float* __restrict__ sump, unsigned* __restrict__ wptr,
                          int2* __restrict__ csr) {
  int e = blockIdx.x * blockDim.x + threadIdx.x;
  if (e >= ETOT) return;
  int s, d;
  float a;
  if (e < NE) {
    s = ei[e];
    d = ei[NE + e];
    a = ea[e];
  } else {
    s = d = e - NE;
    a = sump[0] * (1.0f / NE);
  }
  unsigned pos = atomicAdd(&wptr[d], 1u);
  csr[pos] = make_int2(s, __float_as_int(a));
}

// One wave computes 16 nodes x 64 dims for TWO weight matrices (Wl, Wr).
// X tile staged per-wave in LDS (coalesced global loads), read back as
// same-address ds_read_b128 broadcasts (1 LDS read per 8 FMAs, no shuffles).
template <int K>
__global__ __launch_bounds__(256, 4)
void k_gemm2(const float* __restrict__ X,
             const float* __restrict__ Wl, const float* __restrict__ bl,
             const float* __restrict__ Wr, const float* __restrict__ br,
             float* __restrict__ xl, float* __restrict__ xr) {
  __shared__ float xs[4][16][33];  // [wave][node][32 cols + pad] = 8448 B
  int w = threadIdx.x >> 6;
  int lane = threadIdx.x & 63;
  int n0 = (blockIdx.x * 4 + w) * 16;  // NN % 16 == 0: full waves only
  if (n0 >= NN) return;
  int r = lane >> 2;         // staging row (node) this lane loads
  int c0 = (lane & 3) * 8;   // staging col base (8 floats per lane)
  float accl[16], accr[16];
  #pragma unroll
  for (int m = 0; m < 16; m++) { accl[m] = 0.f; accr[m] = 0.f; }

  constexpr int KB = (K / 32) * 32;
  for (int kb = 0; kb < KB; kb += 32) {
    float4 a0 = *(const float4*)&X[(n0 + r) * K + kb + c0];
    float4 a1 = *(const float4*)&X[(n0 + r) * K + kb + c0 + 4];
    *(float4*)&xs[w][r][c0] = a0;
    *(float4*)&xs[w][r][c0 + 4] = a1;
    // same-wave LDS RAW: compiler-inserted lgkmcnt wait, no barrier needed
    #pragma unroll
    for (int g = 0; g < 8; g++) {
      int k0 = kb + g * 4;
      float wl0 = Wl[(k0 + 0) * DH + lane], wr0 = Wr[(k0 + 0) * DH + lane];
      float wl1 = Wl[(k0 + 1) * DH + lane], wr1 = Wr[(k0 + 1) * DH + lane];
      float wl2 = Wl[(k0 + 2) * DH + lane], wr2 = Wr[(k0 + 2) * DH + lane];
      float wl3 = Wl[(k0 + 3) * DH + lane], wr3 = Wr[(k0 + 3) * DH + lane];
      #pragma unroll
      for (int m = 0; m < 16; m++) {
        float4 xv = *(const float4*)&xs[w][m][g * 4];  // broadcast read
        accl[m] = fmaf(xv.x, wl0, accl[m]); accr[m] = fmaf(xv.x, wr0, accr[m]);
        accl[m] = fmaf(xv.y, wl1, accl[m]); accr[m] = fmaf(xv.y, wr1, accr[m]);
        accl[m] = fmaf(xv.z, wl2, accl[m]); accr[m] = fmaf(xv.z, wr2, accr[m]);
        accl[m] = fmaf(xv.w, wl3, accl[m]); accr[m] = fmaf(xv.w, wr3, accr[m]);
      }
    }
  }
  if constexpr (K > KB) {  // tail: 8 cols (K=264)
    if (lane < 32) {
      int tr = lane >> 1, tc = (lane & 1) * 4;
      *(float4*)&xs[w][tr][tc] = *(const float4*)&X[(n0 + tr) * K + KB + tc];
    }
    #pragma unroll
    for (int g = 0; g < 2; g++) {
      int k0 = KB + g * 4;
      float wl0 = Wl[(k0 + 0) * DH + lane], wr0 = Wr[(k0 + 0) * DH + lane];
      float wl1 = Wl[(k0 + 1) * DH + lane], wr1 = Wr[(k0 + 1) * DH + lane];
      float wl2 = Wl[(k0 + 2) * DH + lane], wr2 = Wr[(k0 + 2) * DH + lane];
      float wl3 = Wl[(k0 + 3) * DH + lane], wr3 = Wr[(k0 + 3) * DH + lane];
      #pragma unroll
      for (int m = 0; m < 16; m++) {
        float4 xv = *(const float4*)&xs[w][m][g * 4];
        accl[m] = fmaf(xv.x, wl0, accl[m]); accr[m] = fmaf(xv.x, wr0, accr[m]);
        accl[m] = fmaf(xv.y, wl1, accl[m]); accr[m] = fmaf(xv.y, wr1, accr[m]);
        accl[m] = fmaf(xv.z, wl2, accl[m]); accr[m] = fmaf(xv.z, wr2, accr[m]);
        accl[m] = fmaf(xv.w, wl3, accl[m]); accr[m] = fmaf(xv.w, wr3, accr[m]);
      }
    }
  }
  float blv = bl[lane], brv = br[lane];
  #pragma unroll
  for (int m = 0; m < 16; m++) {
    xl[(n0 + m) * DH + lane] = accl[m] + blv;
    xr[(n0 + m) * DH + lane] = accr[m] + brv;
  }
}

// Fused per-node attention: 16 lanes own one dst node; online softmax + max-aggregate.
// HEAD=true additionally computes out[n] = relu(h@W3+b3)@W4+b4 (no h write).
template <bool HEAD>
__global__ void k_attn(const unsigned* __restrict__ rowptr, const int2* __restrict__ csr,
                       const float* __restrict__ xl, const float* __restrict__ xr,
                       const float* __restrict__ We, const float* __restrict__ att,
                       const float* __restrict__ bias, float* __restrict__ h,
                       const float* __restrict__ W3, const float* __restrict__ b3,
                       const float* __restrict__ W4, const float* __restrict__ b4,
                       float* __restrict__ out) {
  int n = (blockIdx.x * blockDim.x + threadIdx.x) >> 4;
  int l = threadIdx.x & 15;
  int g0 = threadIdx.x & 48;  // 16-lane group base within the wave
  if (n >= NN) return;        // exact division: never taken
  int l4 = l * 4;
  float4 xr4 = *(const float4*)&xr[n * DH + l4];
  float4 we4 = *(const float4*)&We[l4];
  float4 at4 = *(const float4*)&att[l4];
  int beg = rowptr[n], end = rowptr[n + 1];  // deg >= 1 (self loop)
  float M, D;
  float4 V;
  {  // peel first edge
    int2 c0 = csr[beg];
    float a = __int_as_float(c0.y);
    float4 sl = *(const float4*)&xl[c0.x * DH + l4];
    float v, p = 0.f;
    v = xr4.x + sl.x + a * we4.x; v = v > 0.f ? v : SLOPE * v; p += v * at4.x;
    v = xr4.y + sl.y + a * we4.y; v = v > 0.f ? v : SLOPE * v; p += v * at4.y;
    v = xr4.z + sl.z + a * we4.z; v = v > 0.f ? v : SLOPE * v; p += v * at4.z;
    v = xr4.w + sl.w + a * we4.w; v = v > 0.f ? v : SLOPE * v; p += v * at4.w;
    p += __shfl_xor(p, 1);
    p += __shfl_xor(p, 2);
    p += __shfl_xor(p, 4);
    p += __shfl_xor(p, 8);
    M = p; D = 1.f; V = sl;
  }
  for (int e0 = beg + 1; e0 < end; e0 += 16) {
    int2 cl = csr[min(e0 + l, end - 1)];  // coalesced 128B per group
    int cnt = min(16, end - e0);
    for (int i = 0; i < cnt; i += 4) {
      int mm = min(4, cnt - i);
      float4 sl[4];
      float av[4];
      #pragma unroll
      for (int j = 0; j < 4; j++) {
        if (j < mm) {
          int s = __shfl(cl.x, g0 + i + j);
          av[j] = __int_as_float(__shfl(cl.y, g0 + i + j));
          sl[j] = *(const float4*)&xl[s * DH + l4];  // 4 gathers in flight
        }
      }
      #pragma unroll
      for (int j = 0; j < 4; j++) {
        if (j < mm) {
          float a = av[j];
          float v, p = 0.f;
          v = xr4.x + sl[j].x + a * we4.x; v = v > 0.f ? v : SLOPE * v; p += v * at4.x;
          v = xr4.y + sl[j].y + a * we4.y; v = v > 0.f ? v : SLOPE * v; p += v * at4.y;
          v = xr4.z + sl[j].z + a * we4.z; v = v > 0.f ? v : SLOPE * v; p += v * at4.z;
          v = xr4.w + sl[j].w + a * we4.w; v = v > 0.f ? v : SLOPE * v; p += v * at4.w;
          p += __shfl_xor(p, 1);
          p += __shfl_xor(p, 2);
          p += __shfl_xor(p, 4);
          p += __shfl_xor(p, 8);
          float Mn = fmaxf(M, p);
          float sO = __expf(M - Mn), sN = __expf(p - Mn);
          D = D * sO + sN;
          V.x = fmaxf(V.x * sO, sl[j].x * sN);
          V.y = fmaxf(V.y * sO, sl[j].y * sN);
          V.z = fmaxf(V.z * sO, sl[j].z * sN);
          V.w = fmaxf(V.w * sO, sl[j].w * sN);
          M = Mn;
        }
      }
    }
  }
  float inv = 1.0f / D;
  float4 b = *(const float4*)&bias[l4];
  float4 o;
  o.x = fmaxf(V.x * inv + b.x, 0.f);
  o.y = fmaxf(V.y * inv + b.y, 0.f);
  o.z = fmaxf(V.z * inv + b.z, 0.f);
  o.w = fmaxf(V.w * inv + b.w, 0.f);
  if (!HEAD) {
    *(float4*)&h[n * DH + l4] = o;
  } else {
    // out[n] = relu(o @ W3 + b3) @ W4 + b4 ; lane l owns dims l4..l4+3
    float4 acc = {0.f, 0.f, 0.f, 0.f};
    #pragma unroll
    for (int kk = 0; kk < 16; kk++) {
      float4 hk;
      hk.x = __shfl(o.x, g0 + kk);
      hk.y = __shfl(o.y, g0 + kk);
      hk.z = __shfl(o.z, g0 + kk);
      hk.w = __shfl(o.w, g0 + kk);
      #pragma unroll
      for (int c = 0; c < 4; c++) {
        float4 wv = *(const float4*)&W3[(kk * 4 + c) * DH + l4];
        float hv = (&hk.x)[c];
        acc.x = fmaf(hv, wv.x, acc.x);
        acc.y = fmaf(hv, wv.y, acc.y);
        acc.z = fmaf(hv, wv.z, acc.z);
        acc.w = fmaf(hv, wv.w, acc.w);
      }
    }
    float4 b3v = *(const float4*)&b3[l4];
    float4 w4v = *(const float4*)&W4[l4];
    float t, p = 0.f;
    t = acc.x + b3v.x; t = t > 0.f ? t : 0.f; p += t * w4v.x;
    t = acc.y + b3v.y; t = t > 0.f ? t : 0.f; p += t * w4v.y;
    t = acc.z + b3v.z; t = t > 0.f ? t : 0.f; p += t * w4v.z;
    t = acc.w + b3v.w; t = t > 0.f ? t : 0.f; p += t * w4v.w;
    p += __shfl_xor(p, 1);
    p += __shfl_xor(p, 2);
    p += __shfl_xor(p, 4);
    p += __shfl_xor(p, 8);
    if (l == 0) out[n] = p + b4[0];
  }
}

extern "C" void kernel_launch(void* const* d_in, const int* in_sizes, int n_in,
                              void* d_out, int out_size, void* d_ws, size_t ws_size,
                              hipStream_t stream) {
  const float* x      = (const float*)d_in[0];
  const int*   ei     = (const int*)d_in[1];
  const float* ea     = (const float*)d_in[2];
  const float* l1_Wl  = (const float*)d_in[3];
  const float* l1_bl  = (const float*)d_in[4];
  const float* l1_Wr  = (const float*)d_in[5];
  const float* l1_br  = (const float*)d_in[6];
  const float* l1_We  = (const float*)d_in[7];
  const float* l1_att = (const float*)d_in[8];
  const float* l1_bias= (const float*)d_in[9];
  const float* l2_Wl  = (const float*)d_in[10];
  const float* l2_bl  = (const float*)d_in[11];
  const float* l2_Wr  = (const float*)d_in[12];
  const float* l2_br  = (const float*)d_in[13];
  const float* l2_We  = (const float*)d_in[14];
  const float* l2_att = (const float*)d_in[15];
  const float* l2_bias= (const float*)d_in[16];
  const float* W3     = (const float*)d_in[17];
  const float* b3     = (const float*)d_in[18];
  const float* W4     = (const float*)d_in[19];
  const float* b4     = (const float*)d_in[20];
  float* out = (float*)d_out;

  float*    ws     = (float*)d_ws;
  float*    sum    = ws;                        // 256 floats (only [0] used)
  float*    xl     = ws + 256;                  // NN*DH
  float*    xr     = xl + NN * DH;              // NN*DH
  float*    h      = xr + NN * DH;              // NN*DH
  int2*     csr    = (int2*)(h + NN * DH);      // ETOT int2 (8B aligned)
  unsigned* rowptr = (unsigned*)(csr + ETOT);   // NN+1
  unsigned* wptr   = rowptr + NN + 1;           // NN
  unsigned* deg    = wptr + NN;                 // NN

  const int B = 256;
  const int gemm_blocks = (NN + 63) / 64;           // 1563 (64 nodes/block)
  const int edge_blocks = (ETOT + B - 1) / B;       // 6641
  const int attn_blocks = (NN * 16) / B;            // 6250

  // ---- graph preprocessing (once per call; shared by both layers) ----
  hipMemsetAsync(sum, 0, 256 * sizeof(float), stream);
  hipMemsetAsync(deg, 0, NN * sizeof(unsigned), stream);
  k_mean<<<256, B, 0, stream>>>(ea, sum);
  k_hist<<<edge_blocks, B, 0, stream>>>(ei, deg);
  k_scan<<<1, 1024, 0, stream>>>(deg, rowptr, wptr);
  k_scatter<<<edge_blocks, B, 0, stream>>>(ei, ea, sum, wptr, csr);

  // ---- layer 1 ----
  k_gemm2<DIN><<<gemm_blocks, B, 0, stream>>>(x, l1_Wl, l1_bl, l1_Wr, l1_br, xl, xr);
  k_attn<false><<<attn_blocks, B, 0, stream>>>(rowptr, csr, xl, xr, l1_We, l1_att,
                                               l1_bias, h, W3, b3, W4, b4, out);

  // ---- layer 2 + head (fused) ----
  k_gemm2<DH><<<gemm_blocks, B, 0, stream>>>(h, l2_Wl, l2_bl, l2_Wr, l2_br, xl, xr);
  k_attn<true><<<attn_blocks, B, 0, stream>>>(rowptr, csr, xl, xr, l2_We, l2_att,
                                              l2_bias, h, W3, b3, W4, b4, out);
}

// Round 6
// 1597.811 us; speedup vs baseline: 1.1096x; 1.1096x over previous
//
#include <hip/hip_runtime.h>
#include <math.h>
#include <float.h>

#define NN 100000
#define NE 1600000
#define ETOT 1700000   // NE + NN self loops
#define DIN 264
#define DH 64
#define SLOPE 0.2f

typedef float nativef4 __attribute__((ext_vector_type(4)));

// Fused: edge_attr sum (for self-loop mean) + dst-degree histogram.
__global__ void k_meanhist(const int* __restrict__ ei, const float* __restrict__ ea,
                           float* __restrict__ sum, unsigned* __restrict__ deg) {
  int e = blockIdx.x * blockDim.x + threadIdx.x;
  float a = 0.f;
  if (e < ETOT) {
    int d = (e < NE) ? ei[NE + e] : e - NE;
    atomicAdd(&deg[d], 1u);
    if (e < NE) a = ea[e];
  }
  #pragma unroll
  for (int off = 32; off > 0; off >>= 1) a += __shfl_xor(a, off);
  __shared__ float s[4];
  int lane = threadIdx.x & 63, w = threadIdx.x >> 6;
  if (lane == 0) s[w] = a;
  __syncthreads();
  if (threadIdx.x == 0) atomicAdd(sum, s[0] + s[1] + s[2] + s[3]);
}

// single-block exclusive scan of deg -> rowptr (and wptr cursor copy)
__global__ void k_scan(const unsigned* __restrict__ deg, unsigned* __restrict__ rowptr,
                       unsigned* __restrict__ wptr) {
  __shared__ unsigned ls[1024];
  const int CH = (NN + 1023) / 1024;  // 98
  int t = threadIdx.x;
  int beg = t * CH, end = min(beg + CH, NN);
  unsigned s = 0;
  for (int i = beg; i < end; i++) s += deg[i];
  ls[t] = s;
  __syncthreads();
  for (int off = 1; off < 1024; off <<= 1) {
    unsigned v = (t >= off) ? ls[t - off] : 0u;
    __syncthreads();
    ls[t] += v;
    __syncthreads();
  }
  unsigned base = (t == 0) ? 0u : ls[t - 1];
  for (int i = beg; i < end; i++) {
    rowptr[i] = base;
    wptr[i] = base;
    base += deg[i];
  }
  if (t == 1023) rowptr[NN] = ls[1023];
}

__global__ void k_scatter(const int* __restrict__ ei, const float* __restrict__ ea,
                          const float* __restrict__ sump, unsigned* __restrict__ wptr,
                          int2* __restrict__ csr) {
  int e = blockIdx.x * blockDim.x + threadIdx.x;
  if (e >= ETOT) return;
  int s, d;
  float a;
  if (e < NE) {
    s = ei[e];
    d = ei[NE + e];
    a = ea[e];
  } else {
    s = d = e - NE;
    a = sump[0] * (1.0f / NE);
  }
  unsigned pos = atomicAdd(&wptr[d], 1u);
  csr[pos] = make_int2(s, __float_as_int(a));
}

// One wave computes 8 nodes x 64 dims for TWO weight matrices (Wl, Wr).
// X loads: coalesced 128B per 8-lane group; values broadcast to lanes via shfl.
// (R3-measured best; 16 accums/lane spilled at VGPR=64 — do not widen.)
template <int K>
__global__ void k_gemm2(const float* __restrict__ X,
                        const float* __restrict__ Wl, const float* __restrict__ bl,
                        const float* __restrict__ Wr, const float* __restrict__ br,
                        float* __restrict__ xl, float* __restrict__ xr) {
  int wave = (blockIdx.x * blockDim.x + threadIdx.x) >> 6;
  int lane = threadIdx.x & 63;
  int n0 = wave * 8;  // NN % 8 == 0, exact
  if (n0 >= NN) return;
  int lrow = lane >> 3;        // which of the 8 nodes this lane helps load
  int lcol = (lane & 7) * 4;   // float4 offset within a 32-col chunk
  float accl[8] = {0, 0, 0, 0, 0, 0, 0, 0};
  float accr[8] = {0, 0, 0, 0, 0, 0, 0, 0};
  constexpr int KBF = (K / 32) * 32;
  for (int kb = 0; kb < KBF; kb += 32) {
    nativef4 xv;
    if constexpr (K == DIN)
      xv = __builtin_nontemporal_load(
          (const nativef4*)&X[(n0 + lrow) * K + kb + lcol]);  // x single-use
    else
      xv = *(const nativef4*)&X[(n0 + lrow) * K + kb + lcol];
    #pragma unroll
    for (int kk = 0; kk < 32; kk++) {
      float wl = Wl[(kb + kk) * DH + lane];
      float wr = Wr[(kb + kk) * DH + lane];
      #pragma unroll
      for (int m = 0; m < 8; m++) {
        float bx = __shfl(xv[kk & 3], m * 8 + (kk >> 2));
        accl[m] = fmaf(bx, wl, accl[m]);
        accr[m] = fmaf(bx, wr, accr[m]);
      }
    }
  }
  // tail columns (K=264 -> 8 cols); tiny, uniform loads acceptable here
  for (int k4 = KBF; k4 < K; k4 += 4) {
    float4 xm[8];
    #pragma unroll
    for (int m = 0; m < 8; m++)
      xm[m] = *(const float4*)&X[(n0 + m) * K + k4];
    #pragma unroll
    for (int kk = 0; kk < 4; kk++) {
      float wl = Wl[(k4 + kk) * DH + lane];
      float wr = Wr[(k4 + kk) * DH + lane];
      #pragma unroll
      for (int m = 0; m < 8; m++) {
        float xc = (&xm[m].x)[kk];
        accl[m] = fmaf(xc, wl, accl[m]);
        accr[m] = fmaf(xc, wr, accr[m]);
      }
    }
  }
  #pragma unroll
  for (int m = 0; m < 8; m++) {
    xl[(n0 + m) * DH + lane] = accl[m] + bl[lane];
    xr[(n0 + m) * DH + lane] = accr[m] + br[lane];
  }
}

// Fused per-node attention: 16 lanes own one dst node; online softmax + max-aggregate.
// Gather loop double-buffered: batch b+1's 4 gathers issued before batch b's math.
// HEAD=true additionally computes out[n] = relu(h@W3+b3)@W4+b4 (no h write).
template <bool HEAD>
__global__ void k_attn(const unsigned* __restrict__ rowptr, const int2* __restrict__ csr,
                       const float* __restrict__ xl, const float* __restrict__ xr,
                       const float* __restrict__ We, const float* __restrict__ att,
                       const float* __restrict__ bias, float* __restrict__ h,
                       const float* __restrict__ W3, const float* __restrict__ b3,
                       const float* __restrict__ W4, const float* __restrict__ b4,
                       float* __restrict__ out) {
  int n = (blockIdx.x * blockDim.x + threadIdx.x) >> 4;
  int l = threadIdx.x & 15;
  int g0 = threadIdx.x & 48;  // 16-lane group base within the wave
  if (n >= NN) return;        // exact division: never taken
  int l4 = l * 4;
  float4 xr4 = *(const float4*)&xr[n * DH + l4];
  float4 we4 = *(const float4*)&We[l4];
  float4 at4 = *(const float4*)&att[l4];
  int beg = rowptr[n], end = rowptr[n + 1];  // deg >= 1 (self loop)
  float M, D;
  float4 V;
  {  // peel first edge
    int2 c0 = csr[beg];
    float a = __int_as_float(c0.y);
    float4 sl = *(const float4*)&xl[c0.x * DH + l4];
    float v, p = 0.f;
    v = xr4.x + sl.x + a * we4.x; v = v > 0.f ? v : SLOPE * v; p += v * at4.x;
    v = xr4.y + sl.y + a * we4.y; v = v > 0.f ? v : SLOPE * v; p += v * at4.y;
    v = xr4.z + sl.z + a * we4.z; v = v > 0.f ? v : SLOPE * v; p += v * at4.z;
    v = xr4.w + sl.w + a * we4.w; v = v > 0.f ? v : SLOPE * v; p += v * at4.w;
    p += __shfl_xor(p, 1);
    p += __shfl_xor(p, 2);
    p += __shfl_xor(p, 4);
    p += __shfl_xor(p, 8);
    M = p; D = 1.f; V = sl;
  }
  for (int e0 = beg + 1; e0 < end; e0 += 16) {
    int2 cl = csr[min(e0 + l, end - 1)];  // coalesced 128B per group
    int cnt = min(16, end - e0);
    // prefetch batch 0
    float4 cur[4], nxt[4];
    float acur[4], anxt[4];
    int m0 = min(4, cnt);
    #pragma unroll
    for (int j = 0; j < 4; j++) {
      if (j < m0) {
        int s = __shfl(cl.x, g0 + j);
        acur[j] = __int_as_float(__shfl(cl.y, g0 + j));
        cur[j] = *(const float4*)&xl[s * DH + l4];
      }
    }
    for (int i = 0; i < cnt; i += 4) {
      int mn = min(4, cnt - i - 4);  // may be <=0: no prefetch
      #pragma unroll
      for (int j = 0; j < 4; j++) {
        if (j < mn) {
          int s = __shfl(cl.x, g0 + i + 4 + j);
          anxt[j] = __int_as_float(__shfl(cl.y, g0 + i + 4 + j));
          nxt[j] = *(const float4*)&xl[s * DH + l4];  // in flight under math below
        }
      }
      int mm = min(4, cnt - i);
      #pragma unroll
      for (int j = 0; j < 4; j++) {
        if (j < mm) {
          float a = acur[j];
          float v, p = 0.f;
          v = xr4.x + cur[j].x + a * we4.x; v = v > 0.f ? v : SLOPE * v; p += v * at4.x;
          v = xr4.y + cur[j].y + a * we4.y; v = v > 0.f ? v : SLOPE * v; p += v * at4.y;
          v = xr4.z + cur[j].z + a * we4.z; v = v > 0.f ? v : SLOPE * v; p += v * at4.z;
          v = xr4.w + cur[j].w + a * we4.w; v = v > 0.f ? v : SLOPE * v; p += v * at4.w;
          p += __shfl_xor(p, 1);
          p += __shfl_xor(p, 2);
          p += __shfl_xor(p, 4);
          p += __shfl_xor(p, 8);
          float Mn = fmaxf(M, p);
          float sO = __expf(M - Mn), sN = __expf(p - Mn);
          D = D * sO + sN;
          V.x = fmaxf(V.x * sO, cur[j].x * sN);
          V.y = fmaxf(V.y * sO, cur[j].y * sN);
          V.z = fmaxf(V.z * sO, cur[j].z * sN);
          V.w = fmaxf(V.w * sO, cur[j].w * sN);
          M = Mn;
        }
      }
      #pragma unroll
      for (int j = 0; j < 4; j++) {
        cur[j] = nxt[j];
        acur[j] = anxt[j];
      }
    }
  }
  float inv = 1.0f / D;
  float4 b = *(const float4*)&bias[l4];
  float4 o;
  o.x = fmaxf(V.x * inv + b.x, 0.f);
  o.y = fmaxf(V.y * inv + b.y, 0.f);
  o.z = fmaxf(V.z * inv + b.z, 0.f);
  o.w = fmaxf(V.w * inv + b.w, 0.f);
  if (!HEAD) {
    *(float4*)&h[n * DH + l4] = o;
  } else {
    // out[n] = relu(o @ W3 + b3) @ W4 + b4 ; lane l owns dims l4..l4+3
    float4 acc = {0.f, 0.f, 0.f, 0.f};
    #pragma unroll
    for (int kk = 0; kk < 16; kk++) {
      float4 hk;
      hk.x = __shfl(o.x, g0 + kk);
      hk.y = __shfl(o.y, g0 + kk);
      hk.z = __shfl(o.z, g0 + kk);
      hk.w = __shfl(o.w, g0 + kk);
      #pragma unroll
      for (int c = 0; c < 4; c++) {
        float4 wv = *(const float4*)&W3[(kk * 4 + c) * DH + l4];
        float hv = (&hk.x)[c];
        acc.x = fmaf(hv, wv.x, acc.x);
        acc.y = fmaf(hv, wv.y, acc.y);
        acc.z = fmaf(hv, wv.z, acc.z);
        acc.w = fmaf(hv, wv.w, acc.w);
      }
    }
    float4 b3v = *(const float4*)&b3[l4];
    float4 w4v = *(const float4*)&W4[l4];
    float t, p = 0.f;
    t = acc.x + b3v.x; t = t > 0.f ? t : 0.f; p += t * w4v.x;
    t = acc.y + b3v.y; t = t > 0.f ? t : 0.f; p += t * w4v.y;
    t = acc.z + b3v.z; t = t > 0.f ? t : 0.f; p += t * w4v.z;
    t = acc.w + b3v.w; t = t > 0.f ? t : 0.f; p += t * w4v.w;
    p += __shfl_xor(p, 1);
    p += __shfl_xor(p, 2);
    p += __shfl_xor(p, 4);
    p += __shfl_xor(p, 8);
    if (l == 0) out[n] = p + b4[0];
  }
}

extern "C" void kernel_launch(void* const* d_in, const int* in_sizes, int n_in,
                              void* d_out, int out_size, void* d_ws, size_t ws_size,
                              hipStream_t stream) {
  const float* x      = (const float*)d_in[0];
  const int*   ei     = (const int*)d_in[1];
  const float* ea     = (const float*)d_in[2];
  const float* l1_Wl  = (const float*)d_in[3];
  const float* l1_bl  = (const float*)d_in[4];
  const float* l1_Wr  = (const float*)d_in[5];
  const float* l1_br  = (const float*)d_in[6];
  const float* l1_We  = (const float*)d_in[7];
  const float* l1_att = (const float*)d_in[8];
  const float* l1_bias= (const float*)d_in[9];
  const float* l2_Wl  = (const float*)d_in[10];
  const float* l2_bl  = (const float*)d_in[11];
  const float* l2_Wr  = (const float*)d_in[12];
  const float* l2_br  = (const float*)d_in[13];
  const float* l2_We  = (const float*)d_in[14];
  const float* l2_att = (const float*)d_in[15];
  const float* l2_bias= (const float*)d_in[16];
  const float* W3     = (const float*)d_in[17];
  const float* b3     = (const float*)d_in[18];
  const float* W4     = (const float*)d_in[19];
  const float* b4     = (const float*)d_in[20];
  float* out = (float*)d_out;

  float*    ws     = (float*)d_ws;
  float*    sum    = ws;                        // 256 floats (only [0] used)
  float*    xl     = ws + 256;                  // NN*DH
  float*    xr     = xl + NN * DH;              // NN*DH
  float*    h      = xr + NN * DH;              // NN*DH
  int2*     csr    = (int2*)(h + NN * DH);      // ETOT int2 (8B aligned)
  unsigned* rowptr = (unsigned*)(csr + ETOT);   // NN+1
  unsigned* wptr   = rowptr + NN + 1;           // NN
  unsigned* deg    = wptr + NN;                 // NN

  const int B = 256;
  const int gemm_blocks = (NN / 8 * 64) / B;        // 3125
  const int edge_blocks = (ETOT + B - 1) / B;       // 6641
  const int attn_blocks = (NN * 16) / B;            // 6250

  // ---- graph preprocessing (once per call; shared by both layers) ----
  (void)hipMemsetAsync(sum, 0, 256 * sizeof(float), stream);
  (void)hipMemsetAsync(deg, 0, NN * sizeof(unsigned), stream);
  k_meanhist<<<edge_blocks, B, 0, stream>>>(ei, ea, sum, deg);
  k_scan<<<1, 1024, 0, stream>>>(deg, rowptr, wptr);
  k_scatter<<<edge_blocks, B, 0, stream>>>(ei, ea, sum, wptr, csr);

  // ---- layer 1 ----
  k_gemm2<DIN><<<gemm_blocks, B, 0, stream>>>(x, l1_Wl, l1_bl, l1_Wr, l1_br, xl, xr);
  k_attn<false><<<attn_blocks, B, 0, stream>>>(rowptr, csr, xl, xr, l1_We, l1_att,
                                               l1_bias, h, W3, b3, W4, b4, out);

  // ---- layer 2 + head (fused) ----
  k_gemm2<DH><<<gemm_blocks, B, 0, stream>>>(h, l2_Wl, l2_bl, l2_Wr, l2_br, xl, xr);
  k_attn<true><<<attn_blocks, B, 0, stream>>>(rowptr, csr, xl, xr, l2_We, l2_att,
                                              l2_bias, h, W3, b3, W4, b4, out);
}

// Round 7
// 1551.158 us; speedup vs baseline: 1.1430x; 1.0301x over previous
//
#include <hip/hip_runtime.h>
#include <math.h>
#include <float.h>

#define NN 100000
#define NE 1600000
#define ETOT 1700000   // NE + NN self loops
#define DIN 264
#define DH 64
#define SLOPE 0.2f

// Fused: edge_attr sum (for self-loop mean) + dst-degree histogram.
__global__ void k_meanhist(const int* __restrict__ ei, const float* __restrict__ ea,
                           float* __restrict__ sum, unsigned* __restrict__ deg) {
  int e = blockIdx.x * blockDim.x + threadIdx.x;
  float a = 0.f;
  if (e < ETOT) {
    int d = (e < NE) ? ei[NE + e] : e - NE;
    atomicAdd(&deg[d], 1u);
    if (e < NE) a = ea[e];
  }
  #pragma unroll
  for (int off = 32; off > 0; off >>= 1) a += __shfl_xor(a, off);
  __shared__ float s[4];
  int lane = threadIdx.x & 63, w = threadIdx.x >> 6;
  if (lane == 0) s[w] = a;
  __syncthreads();
  if (threadIdx.x == 0) atomicAdd(sum, s[0] + s[1] + s[2] + s[3]);
}

// single-block exclusive scan of deg -> rowptr (and wptr cursor copy)
__global__ void k_scan(const unsigned* __restrict__ deg, unsigned* __restrict__ rowptr,
                       unsigned* __restrict__ wptr) {
  __shared__ unsigned ls[1024];
  const int CH = (NN + 1023) / 1024;  // 98
  int t = threadIdx.x;
  int beg = t * CH, end = min(beg + CH, NN);
  unsigned s = 0;
  for (int i = beg; i < end; i++) s += deg[i];
  ls[t] = s;
  __syncthreads();
  for (int off = 1; off < 1024; off <<= 1) {
    unsigned v = (t >= off) ? ls[t - off] : 0u;
    __syncthreads();
    ls[t] += v;
    __syncthreads();
  }
  unsigned base = (t == 0) ? 0u : ls[t - 1];
  for (int i = beg; i < end; i++) {
    rowptr[i] = base;
    wptr[i] = base;
    base += deg[i];
  }
  if (t == 1023) rowptr[NN] = ls[1023];
}

__global__ void k_scatter(const int* __restrict__ ei, const float* __restrict__ ea,
                          const float* __restrict__ sump, unsigned* __restrict__ wptr,
                          int2* __restrict__ csr) {
  int e = blockIdx.x * blockDim.x + threadIdx.x;
  if (e >= ETOT) return;
  int s, d;
  float a;
  if (e < NE) {
    s = ei[e];
    d = ei[NE + e];
    a = ea[e];
  } else {
    s = d = e - NE;
    a = sump[0] * (1.0f / NE);
  }
  unsigned pos = atomicAdd(&wptr[d], 1u);
  csr[pos] = make_int2(s, __float_as_int(a));
}

// One wave computes 8 nodes x 64 dims for TWO weight matrices (Wl, Wr).
// X loads: coalesced 128B per 8-lane group; values broadcast to lanes via shfl.
// (R3-measured best; 16 accums/lane spilled at VGPR=64 — do not widen.
//  nontemporal hint on x tested R6: no duration change — dropped.)
template <int K>
__global__ void k_gemm2(const float* __restrict__ X,
                        const float* __restrict__ Wl, const float* __restrict__ bl,
                        const float* __restrict__ Wr, const float* __restrict__ br,
                        float* __restrict__ xl, float* __restrict__ xr) {
  int wave = (blockIdx.x * blockDim.x + threadIdx.x) >> 6;
  int lane = threadIdx.x & 63;
  int n0 = wave * 8;  // NN % 8 == 0, exact
  if (n0 >= NN) return;
  int lrow = lane >> 3;        // which of the 8 nodes this lane helps load
  int lcol = (lane & 7) * 4;   // float4 offset within a 32-col chunk
  float accl[8] = {0, 0, 0, 0, 0, 0, 0, 0};
  float accr[8] = {0, 0, 0, 0, 0, 0, 0, 0};
  constexpr int KBF = (K / 32) * 32;
  for (int kb = 0; kb < KBF; kb += 32) {
    float4 xv = *(const float4*)&X[(n0 + lrow) * K + kb + lcol];
    #pragma unroll
    for (int kk = 0; kk < 32; kk++) {
      float wl = Wl[(kb + kk) * DH + lane];
      float wr = Wr[(kb + kk) * DH + lane];
      #pragma unroll
      for (int m = 0; m < 8; m++) {
        float bx = __shfl((&xv.x)[kk & 3], m * 8 + (kk >> 2));
        accl[m] = fmaf(bx, wl, accl[m]);
        accr[m] = fmaf(bx, wr, accr[m]);
      }
    }
  }
  // tail columns (K=264 -> 8 cols); tiny, uniform loads acceptable here
  for (int k4 = KBF; k4 < K; k4 += 4) {
    float4 xm[8];
    #pragma unroll
    for (int m = 0; m < 8; m++)
      xm[m] = *(const float4*)&X[(n0 + m) * K + k4];
    #pragma unroll
    for (int kk = 0; kk < 4; kk++) {
      float wl = Wl[(k4 + kk) * DH + lane];
      float wr = Wr[(k4 + kk) * DH + lane];
      #pragma unroll
      for (int m = 0; m < 8; m++) {
        float xc = (&xm[m].x)[kk];
        accl[m] = fmaf(xc, wl, accl[m]);
        accr[m] = fmaf(xc, wr, accr[m]);
      }
    }
  }
  #pragma unroll
  for (int m = 0; m < 8; m++) {
    xl[(n0 + m) * DH + lane] = accl[m] + bl[lane];
    xr[(n0 + m) * DH + lane] = accr[m] + br[lane];
  }
}

// Fused per-node attention: 16 lanes own one dst node; online softmax + max-aggregate.
// Edge indices via lane-uniform csr loads (L1 broadcast, no shfl hop);
// 4 gathers issued per batch before any math consumes them.
// HEAD=true additionally computes out[n] = relu(h@W3+b3)@W4+b4 (no h write).
template <bool HEAD>
__global__ void k_attn(const unsigned* __restrict__ rowptr, const int2* __restrict__ csr,
                       const float* __restrict__ xl, const float* __restrict__ xr,
                       const float* __restrict__ We, const float* __restrict__ att,
                       const float* __restrict__ bias, float* __restrict__ h,
                       const float* __restrict__ W3, const float* __restrict__ b3,
                       const float* __restrict__ W4, const float* __restrict__ b4,
                       float* __restrict__ out) {
  int n = (blockIdx.x * blockDim.x + threadIdx.x) >> 4;
  int l = threadIdx.x & 15;
  int g0 = threadIdx.x & 48;  // 16-lane group base within the wave
  if (n >= NN) return;        // exact division: never taken
  int l4 = l * 4;
  float4 xr4 = *(const float4*)&xr[n * DH + l4];
  float4 we4 = *(const float4*)&We[l4];
  float4 at4 = *(const float4*)&att[l4];
  int beg = rowptr[n], end = rowptr[n + 1];  // deg >= 1 (self loop)
  float M, D;
  float4 V;
  {  // peel first edge
    int2 c0 = csr[beg];
    float a = __int_as_float(c0.y);
    float4 sl = *(const float4*)&xl[c0.x * DH + l4];
    float v, p = 0.f;
    v = xr4.x + sl.x + a * we4.x; v = v > 0.f ? v : SLOPE * v; p += v * at4.x;
    v = xr4.y + sl.y + a * we4.y; v = v > 0.f ? v : SLOPE * v; p += v * at4.y;
    v = xr4.z + sl.z + a * we4.z; v = v > 0.f ? v : SLOPE * v; p += v * at4.z;
    v = xr4.w + sl.w + a * we4.w; v = v > 0.f ? v : SLOPE * v; p += v * at4.w;
    p += __shfl_xor(p, 1);
    p += __shfl_xor(p, 2);
    p += __shfl_xor(p, 4);
    p += __shfl_xor(p, 8);
    M = p; D = 1.f; V = sl;
  }
  for (int e0 = beg + 1; e0 < end; e0 += 4) {
    int cnt = min(4, end - e0);
    int2 c[4];
    float4 sl[4];
    #pragma unroll
    for (int j = 0; j < 4; j++)
      if (j < cnt) c[j] = csr[e0 + j];           // uniform 8B loads, L1-broadcast
    #pragma unroll
    for (int j = 0; j < 4; j++)
      if (j < cnt) sl[j] = *(const float4*)&xl[c[j].x * DH + l4];  // 4 in flight
    #pragma unroll
    for (int j = 0; j < 4; j++) {
      if (j < cnt) {
        float a = __int_as_float(c[j].y);
        float v, p = 0.f;
        v = xr4.x + sl[j].x + a * we4.x; v = v > 0.f ? v : SLOPE * v; p += v * at4.x;
        v = xr4.y + sl[j].y + a * we4.y; v = v > 0.f ? v : SLOPE * v; p += v * at4.y;
        v = xr4.z + sl[j].z + a * we4.z; v = v > 0.f ? v : SLOPE * v; p += v * at4.z;
        v = xr4.w + sl[j].w + a * we4.w; v = v > 0.f ? v : SLOPE * v; p += v * at4.w;
        p += __shfl_xor(p, 1);
        p += __shfl_xor(p, 2);
        p += __shfl_xor(p, 4);
        p += __shfl_xor(p, 8);
        float Mn = fmaxf(M, p);
        float sO = __expf(M - Mn), sN = __expf(p - Mn);
        D = D * sO + sN;
        V.x = fmaxf(V.x * sO, sl[j].x * sN);
        V.y = fmaxf(V.y * sO, sl[j].y * sN);
        V.z = fmaxf(V.z * sO, sl[j].z * sN);
        V.w = fmaxf(V.w * sO, sl[j].w * sN);
        M = Mn;
      }
    }
  }
  float inv = 1.0f / D;
  float4 b = *(const float4*)&bias[l4];
  float4 o;
  o.x = fmaxf(V.x * inv + b.x, 0.f);
  o.y = fmaxf(V.y * inv + b.y, 0.f);
  o.z = fmaxf(V.z * inv + b.z, 0.f);
  o.w = fmaxf(V.w * inv + b.w, 0.f);
  if (!HEAD) {
    *(float4*)&h[n * DH + l4] = o;
  } else {
    // out[n] = relu(o @ W3 + b3) @ W4 + b4 ; lane l owns dims l4..l4+3
    float4 acc = {0.f, 0.f, 0.f, 0.f};
    #pragma unroll
    for (int kk = 0; kk < 16; kk++) {
      float4 hk;
      hk.x = __shfl(o.x, g0 + kk);
      hk.y = __shfl(o.y, g0 + kk);
      hk.z = __shfl(o.z, g0 + kk);
      hk.w = __shfl(o.w, g0 + kk);
      #pragma unroll
      for (int c = 0; c < 4; c++) {
        float4 wv = *(const float4*)&W3[(kk * 4 + c) * DH + l4];
        float hv = (&hk.x)[c];
        acc.x = fmaf(hv, wv.x, acc.x);
        acc.y = fmaf(hv, wv.y, acc.y);
        acc.z = fmaf(hv, wv.z, acc.z);
        acc.w = fmaf(hv, wv.w, acc.w);
      }
    }
    float4 b3v = *(const float4*)&b3[l4];
    float4 w4v = *(const float4*)&W4[l4];
    float t, p = 0.f;
    t = acc.x + b3v.x; t = t > 0.f ? t : 0.f; p += t * w4v.x;
    t = acc.y + b3v.y; t = t > 0.f ? t : 0.f; p += t * w4v.y;
    t = acc.z + b3v.z; t = t > 0.f ? t : 0.f; p += t * w4v.z;
    t = acc.w + b3v.w; t = t > 0.f ? t : 0.f; p += t * w4v.w;
    p += __shfl_xor(p, 1);
    p += __shfl_xor(p, 2);
    p += __shfl_xor(p, 4);
    p += __shfl_xor(p, 8);
    if (l == 0) out[n] = p + b4[0];
  }
}

extern "C" void kernel_launch(void* const* d_in, const int* in_sizes, int n_in,
                              void* d_out, int out_size, void* d_ws, size_t ws_size,
                              hipStream_t stream) {
  const float* x      = (const float*)d_in[0];
  const int*   ei     = (const int*)d_in[1];
  const float* ea     = (const float*)d_in[2];
  const float* l1_Wl  = (const float*)d_in[3];
  const float* l1_bl  = (const float*)d_in[4];
  const float* l1_Wr  = (const float*)d_in[5];
  const float* l1_br  = (const float*)d_in[6];
  const float* l1_We  = (const float*)d_in[7];
  const float* l1_att = (const float*)d_in[8];
  const float* l1_bias= (const float*)d_in[9];
  const float* l2_Wl  = (const float*)d_in[10];
  const float* l2_bl  = (const float*)d_in[11];
  const float* l2_Wr  = (const float*)d_in[12];
  const float* l2_br  = (const float*)d_in[13];
  const float* l2_We  = (const float*)d_in[14];
  const float* l2_att = (const float*)d_in[15];
  const float* l2_bias= (const float*)d_in[16];
  const float* W3     = (const float*)d_in[17];
  const float* b3     = (const float*)d_in[18];
  const float* W4     = (const float*)d_in[19];
  const float* b4     = (const float*)d_in[20];
  float* out = (float*)d_out;

  float*    ws     = (float*)d_ws;
  float*    sum    = ws;                        // 256 floats (only [0] used)
  float*    xl     = ws + 256;                  // NN*DH
  float*    xr     = xl + NN * DH;              // NN*DH
  float*    h      = xr + NN * DH;              // NN*DH
  int2*     csr    = (int2*)(h + NN * DH);      // ETOT int2 (8B aligned)
  unsigned* rowptr = (unsigned*)(csr + ETOT);   // NN+1
  unsigned* wptr   = rowptr + NN + 1;           // NN
  unsigned* deg    = wptr + NN;                 // NN

  const int B = 256;
  const int gemm_blocks = (NN / 8 * 64) / B;        // 3125
  const int edge_blocks = (ETOT + B - 1) / B;       // 6641
  const int attn_blocks = (NN * 16) / B;            // 6250

  // ---- graph preprocessing (once per call; shared by both layers) ----
  (void)hipMemsetAsync(sum, 0, 256 * sizeof(float), stream);
  (void)hipMemsetAsync(deg, 0, NN * sizeof(unsigned), stream);
  k_meanhist<<<edge_blocks, B, 0, stream>>>(ei, ea, sum, deg);
  k_scan<<<1, 1024, 0, stream>>>(deg, rowptr, wptr);
  k_scatter<<<edge_blocks, B, 0, stream>>>(ei, ea, sum, wptr, csr);

  // ---- layer 1 ----
  k_gemm2<DIN><<<gemm_blocks, B, 0, stream>>>(x, l1_Wl, l1_bl, l1_Wr, l1_br, xl, xr);
  k_attn<false><<<attn_blocks, B, 0, stream>>>(rowptr, csr, xl, xr, l1_We, l1_att,
                                               l1_bias, h, W3, b3, W4, b4, out);

  // ---- layer 2 + head (fused) ----
  k_gemm2<DH><<<gemm_blocks, B, 0, stream>>>(h, l2_Wl, l2_bl, l2_Wr, l2_br, xl, xr);
  k_attn<true><<<attn_blocks, B, 0, stream>>>(rowptr, csr, xl, xr, l2_We, l2_att,
                                              l2_bias, h, W3, b3, W4, b4, out);
}

// Round 8
// 1510.127 us; speedup vs baseline: 1.1740x; 1.0272x over previous
//
#include <hip/hip_runtime.h>
#include <math.h>
#include <float.h>

#define NN 100000
#define NE 1600000
#define ETOT 1700000   // NE + NN self loops
#define DIN 264
#define DH 64
#define SLOPE 0.2f

__global__ void k_mean(const float* __restrict__ ea, float* __restrict__ sum) {
  float acc = 0.f;
  for (int i = blockIdx.x * blockDim.x + threadIdx.x; i < NE; i += gridDim.x * blockDim.x)
    acc += ea[i];
  #pragma unroll
  for (int off = 32; off > 0; off >>= 1) acc += __shfl_xor(acc, off);
  __shared__ float s[4];
  int lane = threadIdx.x & 63, w = threadIdx.x >> 6;
  if (lane == 0) s[w] = acc;
  __syncthreads();
  if (threadIdx.x == 0) atomicAdd(sum, s[0] + s[1] + s[2] + s[3]);
}

__global__ void k_hist(const int* __restrict__ ei, unsigned* __restrict__ deg) {
  int e = blockIdx.x * blockDim.x + threadIdx.x;
  if (e >= ETOT) return;
  int d = (e < NE) ? ei[NE + e] : e - NE;
  atomicAdd(&deg[d], 1u);
}

// single-block exclusive scan of deg -> rowptr (and wptr cursor copy)
__global__ void k_scan(const unsigned* __restrict__ deg, unsigned* __restrict__ rowptr,
                       unsigned* __restrict__ wptr) {
  __shared__ unsigned ls[1024];
  const int CH = (NN + 1023) / 1024;  // 98
  int t = threadIdx.x;
  int beg = t * CH, end = min(beg + CH, NN);
  unsigned s = 0;
  for (int i = beg; i < end; i++) s += deg[i];
  ls[t] = s;
  __syncthreads();
  for (int off = 1; off < 1024; off <<= 1) {
    unsigned v = (t >= off) ? ls[t - off] : 0u;
    __syncthreads();
    ls[t] += v;
    __syncthreads();
  }
  unsigned base = (t == 0) ? 0u : ls[t - 1];
  for (int i = beg; i < end; i++) {
    rowptr[i] = base;
    wptr[i] = base;
    base += deg[i];
  }
  if (t == 1023) rowptr[NN] = ls[1023];
}

__global__ void k_scatter(const int* __restrict__ ei, const float* __restrict__ ea,
                          const float* __restrict__ sump, unsigned* __restrict__ wptr,
                          int2* __restrict__ csr) {
  int e = blockIdx.x * blockDim.x + threadIdx.x;
  if (e >= ETOT) return;
  int s, d;
  float a;
  if (e < NE) {
    s = ei[e];
    d = ei[NE + e];
    a = ea[e];
  } else {
    s = d = e - NE;
    a = sump[0] * (1.0f / NE);
  }
  unsigned pos = atomicAdd(&wptr[d], 1u);
  csr[pos] = make_int2(s, __float_as_int(a));
}

// One wave computes 8 nodes x 64 dims for TWO weight matrices (Wl, Wr).
// X loads: coalesced 128B per 8-lane group; values broadcast to lanes via shfl.
// (R3-measured best. Do not widen to 16 nodes (spills at VGPR=64, R4);
//  LDS staging regressed (R4); nontemporal hint neutral (R6).)
template <int K>
__global__ void k_gemm2(const float* __restrict__ X,
                        const float* __restrict__ Wl, const float* __restrict__ bl,
                        const float* __restrict__ Wr, const float* __restrict__ br,
                        float* __restrict__ xl, float* __restrict__ xr) {
  int wave = (blockIdx.x * blockDim.x + threadIdx.x) >> 6;
  int lane = threadIdx.x & 63;
  int n0 = wave * 8;  // NN % 8 == 0, exact
  if (n0 >= NN) return;
  int lrow = lane >> 3;        // which of the 8 nodes this lane helps load
  int lcol = (lane & 7) * 4;   // float4 offset within a 32-col chunk
  float accl[8] = {0, 0, 0, 0, 0, 0, 0, 0};
  float accr[8] = {0, 0, 0, 0, 0, 0, 0, 0};
  constexpr int KBF = (K / 32) * 32;
  for (int kb = 0; kb < KBF; kb += 32) {
    float4 xv = *(const float4*)&X[(n0 + lrow) * K + kb + lcol];
    #pragma unroll
    for (int kk = 0; kk < 32; kk++) {
      float wl = Wl[(kb + kk) * DH + lane];
      float wr = Wr[(kb + kk) * DH + lane];
      #pragma unroll
      for (int m = 0; m < 8; m++) {
        float bx = __shfl((&xv.x)[kk & 3], m * 8 + (kk >> 2));
        accl[m] = fmaf(bx, wl, accl[m]);
        accr[m] = fmaf(bx, wr, accr[m]);
      }
    }
  }
  // tail columns (K=264 -> 8 cols); tiny, uniform loads acceptable here
  for (int k4 = KBF; k4 < K; k4 += 4) {
    float4 xm[8];
    #pragma unroll
    for (int m = 0; m < 8; m++)
      xm[m] = *(const float4*)&X[(n0 + m) * K + k4];
    #pragma unroll
    for (int kk = 0; kk < 4; kk++) {
      float wl = Wl[(k4 + kk) * DH + lane];
      float wr = Wr[(k4 + kk) * DH + lane];
      #pragma unroll
      for (int m = 0; m < 8; m++) {
        float xc = (&xm[m].x)[kk];
        accl[m] = fmaf(xc, wl, accl[m]);
        accr[m] = fmaf(xc, wr, accr[m]);
      }
    }
  }
  #pragma unroll
  for (int m = 0; m < 8; m++) {
    xl[(n0 + m) * DH + lane] = accl[m] + bl[lane];
    xr[(n0 + m) * DH + lane] = accr[m] + br[lane];
  }
}

// Fused per-node attention: 16 lanes own one dst node; online softmax + max-aggregate.
// R3-measured best edge loop: 16-edge coalesced csr chunk + shfl index broadcast,
// 4 gathers issued per batch. (Double-buffering regressed (R6); lane-uniform
// csr loads regressed (R7).)
// HEAD=true additionally computes out[n] = relu(h@W3+b3)@W4+b4 (no h write).
template <bool HEAD>
__global__ void k_attn(const unsigned* __restrict__ rowptr, const int2* __restrict__ csr,
                       const float* __restrict__ xl, const float* __restrict__ xr,
                       const float* __restrict__ We, const float* __restrict__ att,
                       const float* __restrict__ bias, float* __restrict__ h,
                       const float* __restrict__ W3, const float* __restrict__ b3,
                       const float* __restrict__ W4, const float* __restrict__ b4,
                       float* __restrict__ out) {
  int n = (blockIdx.x * blockDim.x + threadIdx.x) >> 4;
  int l = threadIdx.x & 15;
  int g0 = threadIdx.x & 48;  // 16-lane group base within the wave
  if (n >= NN) return;        // exact division: never taken
  int l4 = l * 4;
  float4 xr4 = *(const float4*)&xr[n * DH + l4];
  float4 we4 = *(const float4*)&We[l4];
  float4 at4 = *(const float4*)&att[l4];
  int beg = rowptr[n], end = rowptr[n + 1];  // deg >= 1 (self loop)
  float M, D;
  float4 V;
  {  // peel first edge
    int2 c0 = csr[beg];
    float a = __int_as_float(c0.y);
    float4 sl = *(const float4*)&xl[c0.x * DH + l4];
    float v, p = 0.f;
    v = xr4.x + sl.x + a * we4.x; v = v > 0.f ? v : SLOPE * v; p += v * at4.x;
    v = xr4.y + sl.y + a * we4.y; v = v > 0.f ? v : SLOPE * v; p += v * at4.y;
    v = xr4.z + sl.z + a * we4.z; v = v > 0.f ? v : SLOPE * v; p += v * at4.z;
    v = xr4.w + sl.w + a * we4.w; v = v > 0.f ? v : SLOPE * v; p += v * at4.w;
    p += __shfl_xor(p, 1);
    p += __shfl_xor(p, 2);
    p += __shfl_xor(p, 4);
    p += __shfl_xor(p, 8);
    M = p; D = 1.f; V = sl;
  }
  for (int e0 = beg + 1; e0 < end; e0 += 16) {
    int2 cl = csr[min(e0 + l, end - 1)];  // coalesced 128B per group
    int cnt = min(16, end - e0);
    for (int i = 0; i < cnt; i += 4) {
      int mm = min(4, cnt - i);
      float4 sl[4];
      float av[4];
      #pragma unroll
      for (int j = 0; j < 4; j++) {
        if (j < mm) {
          int s = __shfl(cl.x, g0 + i + j);
          av[j] = __int_as_float(__shfl(cl.y, g0 + i + j));
          sl[j] = *(const float4*)&xl[s * DH + l4];  // 4 gathers in flight
        }
      }
      #pragma unroll
      for (int j = 0; j < 4; j++) {
        if (j < mm) {
          float a = av[j];
          float v, p = 0.f;
          v = xr4.x + sl[j].x + a * we4.x; v = v > 0.f ? v : SLOPE * v; p += v * at4.x;
          v = xr4.y + sl[j].y + a * we4.y; v = v > 0.f ? v : SLOPE * v; p += v * at4.y;
          v = xr4.z + sl[j].z + a * we4.z; v = v > 0.f ? v : SLOPE * v; p += v * at4.z;
          v = xr4.w + sl[j].w + a * we4.w; v = v > 0.f ? v : SLOPE * v; p += v * at4.w;
          p += __shfl_xor(p, 1);
          p += __shfl_xor(p, 2);
          p += __shfl_xor(p, 4);
          p += __shfl_xor(p, 8);
          float Mn = fmaxf(M, p);
          float sO = __expf(M - Mn), sN = __expf(p - Mn);
          D = D * sO + sN;
          V.x = fmaxf(V.x * sO, sl[j].x * sN);
          V.y = fmaxf(V.y * sO, sl[j].y * sN);
          V.z = fmaxf(V.z * sO, sl[j].z * sN);
          V.w = fmaxf(V.w * sO, sl[j].w * sN);
          M = Mn;
        }
      }
    }
  }
  float inv = 1.0f / D;
  float4 b = *(const float4*)&bias[l4];
  float4 o;
  o.x = fmaxf(V.x * inv + b.x, 0.f);
  o.y = fmaxf(V.y * inv + b.y, 0.f);
  o.z = fmaxf(V.z * inv + b.z, 0.f);
  o.w = fmaxf(V.w * inv + b.w, 0.f);
  if (!HEAD) {
    *(float4*)&h[n * DH + l4] = o;
  } else {
    // out[n] = relu(o @ W3 + b3) @ W4 + b4 ; lane l owns dims l4..l4+3
    float4 acc = {0.f, 0.f, 0.f, 0.f};
    #pragma unroll
    for (int kk = 0; kk < 16; kk++) {
      float4 hk;
      hk.x = __shfl(o.x, g0 + kk);
      hk.y = __shfl(o.y, g0 + kk);
      hk.z = __shfl(o.z, g0 + kk);
      hk.w = __shfl(o.w, g0 + kk);
      #pragma unroll
      for (int c = 0; c < 4; c++) {
        float4 wv = *(const float4*)&W3[(kk * 4 + c) * DH + l4];
        float hv = (&hk.x)[c];
        acc.x = fmaf(hv, wv.x, acc.x);
        acc.y = fmaf(hv, wv.y, acc.y);
        acc.z = fmaf(hv, wv.z, acc.z);
        acc.w = fmaf(hv, wv.w, acc.w);
      }
    }
    float4 b3v = *(const float4*)&b3[l4];
    float4 w4v = *(const float4*)&W4[l4];
    float t, p = 0.f;
    t = acc.x + b3v.x; t = t > 0.f ? t : 0.f; p += t * w4v.x;
    t = acc.y + b3v.y; t = t > 0.f ? t : 0.f; p += t * w4v.y;
    t = acc.z + b3v.z; t = t > 0.f ? t : 0.f; p += t * w4v.z;
    t = acc.w + b3v.w; t = t > 0.f ? t : 0.f; p += t * w4v.w;
    p += __shfl_xor(p, 1);
    p += __shfl_xor(p, 2);
    p += __shfl_xor(p, 4);
    p += __shfl_xor(p, 8);
    if (l == 0) out[n] = p + b4[0];
  }
}

extern "C" void kernel_launch(void* const* d_in, const int* in_sizes, int n_in,
                              void* d_out, int out_size, void* d_ws, size_t ws_size,
                              hipStream_t stream) {
  const float* x      = (const float*)d_in[0];
  const int*   ei     = (const int*)d_in[1];
  const float* ea     = (const float*)d_in[2];
  const float* l1_Wl  = (const float*)d_in[3];
  const float* l1_bl  = (const float*)d_in[4];
  const float* l1_Wr  = (const float*)d_in[5];
  const float* l1_br  = (const float*)d_in[6];
  const float* l1_We  = (const float*)d_in[7];
  const float* l1_att = (const float*)d_in[8];
  const float* l1_bias= (const float*)d_in[9];
  const float* l2_Wl  = (const float*)d_in[10];
  const float* l2_bl  = (const float*)d_in[11];
  const float* l2_Wr  = (const float*)d_in[12];
  const float* l2_br  = (const float*)d_in[13];
  const float* l2_We  = (const float*)d_in[14];
  const float* l2_att = (const float*)d_in[15];
  const float* l2_bias= (const float*)d_in[16];
  const float* W3     = (const float*)d_in[17];
  const float* b3     = (const float*)d_in[18];
  const float* W4     = (const float*)d_in[19];
  const float* b4     = (const float*)d_in[20];
  float* out = (float*)d_out;

  float*    ws     = (float*)d_ws;
  float*    sum    = ws;                        // 256 floats (only [0] used)
  float*    xl     = ws + 256;                  // NN*DH
  float*    xr     = xl + NN * DH;              // NN*DH
  float*    h      = xr + NN * DH;              // NN*DH
  int2*     csr    = (int2*)(h + NN * DH);      // ETOT int2 (8B aligned)
  unsigned* rowptr = (unsigned*)(csr + ETOT);   // NN+1
  unsigned* wptr   = rowptr + NN + 1;           // NN
  unsigned* deg    = wptr + NN;                 // NN

  const int B = 256;
  const int gemm_blocks = (NN / 8 * 64) / B;        // 3125
  const int edge_blocks = (ETOT + B - 1) / B;       // 6641
  const int attn_blocks = (NN * 16) / B;            // 6250

  // ---- graph preprocessing (once per call; shared by both layers) ----
  (void)hipMemsetAsync(sum, 0, 256 * sizeof(float), stream);
  (void)hipMemsetAsync(deg, 0, NN * sizeof(unsigned), stream);
  k_mean<<<256, B, 0, stream>>>(ea, sum);
  k_hist<<<edge_blocks, B, 0, stream>>>(ei, deg);
  k_scan<<<1, 1024, 0, stream>>>(deg, rowptr, wptr);
  k_scatter<<<edge_blocks, B, 0, stream>>>(ei, ea, sum, wptr, csr);

  // ---- layer 1 ----
  k_gemm2<DIN><<<gemm_blocks, B, 0, stream>>>(x, l1_Wl, l1_bl, l1_Wr, l1_br, xl, xr);
  k_attn<false><<<attn_blocks, B, 0, stream>>>(rowptr, csr, xl, xr, l1_We, l1_att,
                                               l1_bias, h, W3, b3, W4, b4, out);

  // ---- layer 2 + head (fused) ----
  k_gemm2<DH><<<gemm_blocks, B, 0, stream>>>(h, l2_Wl, l2_bl, l2_Wr, l2_br, xl, xr);
  k_attn<true><<<attn_blocks, B, 0, stream>>>(rowptr, csr, xl, xr, l2_We, l2_att,
                                              l2_bias, h, W3, b3, W4, b4, out);
}